// Round 2
// baseline (1276.343 us; speedup 1.0000x reference)
//
#include <hip/hip_runtime.h>

#define BB 16
#define TT 12
#define NN 1024
#define DD 64
#define EE 32
#define MM (TT*NN)          // 12288 rows per batch
#define ROWS (BB*MM)        // 196608 total rows
#define CPB2 64             // blocks per batch for K2 (64*4 waves*48 rows = 12288)
#define CPB4 96             // blocks per batch for K4 (96*4 waves*32 rows = 12288)
#define LN_EPS 1e-5f

__device__ __forceinline__ float wave_sum64(float v){
  #pragma unroll
  for (int off = 32; off; off >>= 1) v += __shfl_xor(v, off);
  return v;
}

// ---------------- K1: fused STGCN ----------------
// u = 0.5*(x[t-1]+x[t]); g1=u@W1^T+b1; g2=u@W2^T+b2; h=relu(g1*g2)+g1; out1=LN(h+x)
// W rows pinned in VGPRs (asm barrier defeats load sinking); 2 rows/iter, 16 FMA chains.
__global__ __launch_bounds__(256, 2)
void k1_stgcn(const float* __restrict__ x,
              const float* __restrict__ W1, const float* __restrict__ b1,
              const float* __restrict__ W2, const float* __restrict__ b2,
              const float* __restrict__ lng, const float* __restrict__ lnb,
              float* __restrict__ out1)
{
  __shared__ __align__(16) float ubuf[4][2][DD];
  const int lane = threadIdx.x & 63;
  const int wid  = threadIdx.x >> 6;

  float w1[DD], w2[DD];
  #pragma unroll
  for (int j = 0; j < DD/4; ++j){
    float4 a = *reinterpret_cast<const float4*>(W1 + lane*DD + 4*j);
    w1[4*j+0]=a.x; w1[4*j+1]=a.y; w1[4*j+2]=a.z; w1[4*j+3]=a.w;
    float4 c = *reinterpret_cast<const float4*>(W2 + lane*DD + 4*j);
    w2[4*j+0]=c.x; w2[4*j+1]=c.y; w2[4*j+2]=c.z; w2[4*j+3]=c.w;
  }
  // pin: force W into VGPRs for the whole kernel (no remat/sinking)
  #pragma unroll
  for (int j = 0; j < DD; ++j) asm volatile("" : "+v"(w1[j]), "+v"(w2[j]));

  const float bb1 = b1[lane], bb2 = b2[lane];
  const float gam = lng[lane], bet = lnb[lane];

  auto loadpair = [&](int r, float& xa, float& xb, float& ua, float& ub){
    {
      const int t = (r >> 10) % TT;
      const size_t base = (size_t)r * DD + lane;
      const float xc = x[base];
      const float xp = (t > 0) ? x[base - (size_t)NN*DD] : 0.f;
      xa = xc; ua = 0.5f*(xc + xp);
    }
    {
      const int r1 = r + 1;
      const int t = (r1 >> 10) % TT;
      const size_t base = (size_t)r1 * DD + lane;
      const float xc = x[base];
      const float xp = (t > 0) ? x[base - (size_t)NN*DD] : 0.f;
      xb = xc; ub = 0.5f*(xc + xp);
    }
  };

  const int wstride = gridDim.x * 8;            // rows per grid step
  int r0 = (blockIdx.x*4 + wid)*2;
  if (r0 >= ROWS) return;

  float xcA, xcB, uA, uB;
  loadpair(r0, xcA, xcB, uA, uB);

  while (true){
    ubuf[wid][0][lane] = uA;
    ubuf[wid][1][lane] = uB;
    __builtin_amdgcn_wave_barrier();

    // prefetch next pair while FMAs run
    const int r_next = r0 + wstride;
    const bool havenext = (r_next < ROWS);
    float nxA=0.f, nxB=0.f, nuA=0.f, nuB=0.f;
    if (havenext) loadpair(r_next, nxA, nxB, nuA, nuB);

    float p1A[4], p2A[4], p1B[4], p2B[4];
    #pragma unroll
    for (int c = 0; c < 4; ++c){ p1A[c]=0.f; p2A[c]=0.f; p1B[c]=0.f; p2B[c]=0.f; }
    #pragma unroll
    for (int c = 0; c < 4; ++c){
      #pragma unroll
      for (int q = 0; q < 4; ++q){
        const int j = c*16 + q*4;
        const float4 ua4 = *reinterpret_cast<const float4*>(&ubuf[wid][0][j]);
        const float4 ub4 = *reinterpret_cast<const float4*>(&ubuf[wid][1][j]);
        p1A[c] = fmaf(ua4.x, w1[j+0], p1A[c]);  p2A[c] = fmaf(ua4.x, w2[j+0], p2A[c]);
        p1B[c] = fmaf(ub4.x, w1[j+0], p1B[c]);  p2B[c] = fmaf(ub4.x, w2[j+0], p2B[c]);
        p1A[c] = fmaf(ua4.y, w1[j+1], p1A[c]);  p2A[c] = fmaf(ua4.y, w2[j+1], p2A[c]);
        p1B[c] = fmaf(ub4.y, w1[j+1], p1B[c]);  p2B[c] = fmaf(ub4.y, w2[j+1], p2B[c]);
        p1A[c] = fmaf(ua4.z, w1[j+2], p1A[c]);  p2A[c] = fmaf(ua4.z, w2[j+2], p2A[c]);
        p1B[c] = fmaf(ub4.z, w1[j+2], p1B[c]);  p2B[c] = fmaf(ub4.z, w2[j+2], p2B[c]);
        p1A[c] = fmaf(ua4.w, w1[j+3], p1A[c]);  p2A[c] = fmaf(ua4.w, w2[j+3], p2A[c]);
        p1B[c] = fmaf(ub4.w, w1[j+3], p1B[c]);  p2B[c] = fmaf(ub4.w, w2[j+3], p2B[c]);
      }
    }
    const float g1A = (p1A[0]+p1A[1])+(p1A[2]+p1A[3]) + bb1;
    const float g2A = (p2A[0]+p2A[1])+(p2A[2]+p2A[3]) + bb2;
    const float g1B = (p1B[0]+p1B[1])+(p1B[2]+p1B[3]) + bb1;
    const float g2B = (p2B[0]+p2B[1])+(p2B[2]+p2B[3]) + bb2;

    // LN for both rows (independent shfl chains interleave)
    const float sA = fmaxf(g1A*g2A, 0.f) + g1A + xcA;
    const float sB = fmaxf(g1B*g2B, 0.f) + g1B + xcB;
    const float mA = wave_sum64(sA) * (1.f/DD);
    const float mB = wave_sum64(sB) * (1.f/DD);
    const float dA = sA - mA, dB = sB - mB;
    const float vA = wave_sum64(dA*dA) * (1.f/DD);
    const float vB = wave_sum64(dB*dB) * (1.f/DD);
    out1[(size_t)r0*DD + lane]      = dA * rsqrtf(vA + LN_EPS) * gam + bet;
    out1[(size_t)(r0+1)*DD + lane]  = dB * rsqrtf(vB + LN_EPS) * gam + bet;

    if (!havenext) break;
    r0 = r_next;
    xcA = nxA; xcB = nxB; uA = nuA; uB = nuB;
  }
}

// ---------------- K2: assign = softmax(x @ edge_clf); hf[b,e,d] += a[m,e]*x[m,d] ----------------
__global__ __launch_bounds__(256, 2)
void k2_hyper1(const float* __restrict__ x, const float* __restrict__ clf,
               float* __restrict__ assign_ws, float* __restrict__ hf)
{
  __shared__ __align__(16) float xbuf[4][DD];
  __shared__ __align__(16) float abuf[4][EE];
  __shared__ __align__(16) float red[4][EE][DD];   // 32 KB: block-level hf reduce
  const int lane = threadIdx.x & 63;
  const int wid  = threadIdx.x >> 6;
  const int b = blockIdx.x / CPB2;
  const int chunk = blockIdx.x % CPB2;
  const int e = lane & 31;
  const int half = lane >> 5;

  float clfreg[EE];
  #pragma unroll
  for (int j = 0; j < EE; ++j) clfreg[j] = clf[(half*32 + j)*EE + e];
  #pragma unroll
  for (int j = 0; j < EE; ++j) asm volatile("" : "+v"(clfreg[j]));

  float hfacc[EE];
  #pragma unroll
  for (int j = 0; j < EE; ++j) hfacc[j] = 0.f;

  const int rpw = (MM / CPB2) / 4;   // 48 rows per wave
  for (int it = 0; it < rpw; ++it){
    const int mrow = chunk*(MM/CPB2) + wid*rpw + it;
    const size_t ridx = (size_t)b*MM + mrow;
    const float xv = x[ridx*DD + lane];
    xbuf[wid][lane] = xv;
    __builtin_amdgcn_wave_barrier();
    float pt[4] = {0.f,0.f,0.f,0.f};
    #pragma unroll
    for (int j = 0; j < 8; ++j){
      const float4 uv = *reinterpret_cast<const float4*>(&xbuf[wid][half*32 + 4*j]);
      pt[0] = fmaf(uv.x, clfreg[4*j+0], pt[0]);
      pt[1] = fmaf(uv.y, clfreg[4*j+1], pt[1]);
      pt[2] = fmaf(uv.z, clfreg[4*j+2], pt[2]);
      pt[3] = fmaf(uv.w, clfreg[4*j+3], pt[3]);
    }
    const float part = (pt[0]+pt[1]) + (pt[2]+pt[3]);
    const float logit = part + __shfl_xor(part, 32);
    float mx = logit;
    #pragma unroll
    for (int off = 16; off; off >>= 1) mx = fmaxf(mx, __shfl_xor(mx, off));
    const float ex = expf(logit - mx);
    float sm = ex;
    #pragma unroll
    for (int off = 16; off; off >>= 1) sm += __shfl_xor(sm, off);
    const float a = ex / sm;
    if (half == 0) assign_ws[ridx*EE + e] = a;
    abuf[wid][e] = a;
    __builtin_amdgcn_wave_barrier();
    #pragma unroll
    for (int j = 0; j < 8; ++j){
      const float4 av = *reinterpret_cast<const float4*>(&abuf[wid][4*j]);
      hfacc[4*j+0] = fmaf(av.x, xv, hfacc[4*j+0]);
      hfacc[4*j+1] = fmaf(av.y, xv, hfacc[4*j+1]);
      hfacc[4*j+2] = fmaf(av.z, xv, hfacc[4*j+2]);
      hfacc[4*j+3] = fmaf(av.w, xv, hfacc[4*j+3]);
    }
    __builtin_amdgcn_wave_barrier();
  }
  // block-level reduce across 4 waves, then one atomic set per block
  #pragma unroll
  for (int j = 0; j < EE; ++j) red[wid][j][lane] = hfacc[j];
  __syncthreads();
  const float* rf = &red[0][0][0];
  for (int k = threadIdx.x; k < EE*DD; k += 256){
    const float s = (rf[k] + rf[EE*DD + k]) + (rf[2*EE*DD + k] + rf[3*EE*DD + k]);
    atomicAdd(&hf[(size_t)b*EE*DD + k], s);
  }
}

// ---------------- K3: hyper_out = relu(edge_map @ hf) + hf ----------------
__global__ void k3_edge(const float* __restrict__ hf, const float* __restrict__ em,
                        float* __restrict__ ho)
{
  __shared__ float ems[EE*EE];
  __shared__ float hfs[EE*DD];
  const int b = blockIdx.x;
  const int tid = threadIdx.x;
  for (int i = tid; i < EE*EE; i += 256) ems[i] = em[i];
  for (int i = tid; i < EE*DD; i += 256) hfs[i] = hf[(size_t)b*EE*DD + i];
  __syncthreads();
  for (int i = tid; i < EE*DD; i += 256){
    const int e = i >> 6, d = i & 63;
    float acc = 0.f;
    #pragma unroll
    for (int f = 0; f < EE; ++f) acc = fmaf(ems[e*EE+f], hfs[f*DD+d], acc);
    ho[(size_t)b*EE*DD + i] = fmaxf(acc, 0.f) + hfs[e*DD+d];
  }
}

// ---------------- K4: y = relu(assign @ hyper_out); out2 = LN(y+x); xout = 0.5*(out1+out2) ----------------
__global__ __launch_bounds__(256, 4)
void k4_combine(const float* __restrict__ x, const float* __restrict__ out1,
                const float* __restrict__ assign_ws, const float* __restrict__ ho,
                const float* __restrict__ hg, const float* __restrict__ hb,
                float* __restrict__ xout)
{
  __shared__ __align__(16) float hos[EE*DD];
  __shared__ __align__(16) float abuf[4][EE];
  const int lane = threadIdx.x & 63;
  const int wid  = threadIdx.x >> 6;
  const int b = blockIdx.x / CPB4;
  const int chunk = blockIdx.x % CPB4;
  for (int i = threadIdx.x; i < EE*DD; i += 256) hos[i] = ho[(size_t)b*EE*DD + i];
  __syncthreads();
  const float gam = hg[lane], bet = hb[lane];
  const int rpw = (MM / CPB4) / 4;   // 32 rows per wave
  for (int it = 0; it < rpw; ++it){
    const int mrow = chunk*(MM/CPB4) + wid*rpw + it;
    const size_t ridx = (size_t)b*MM + mrow;
    const float xc = x[ridx*DD + lane];
    const float o1 = out1[ridx*DD + lane];
    if (lane < EE) abuf[wid][lane] = assign_ws[ridx*EE + lane];
    __builtin_amdgcn_wave_barrier();
    float y0=0.f, y1=0.f, y2=0.f, y3=0.f;
    #pragma unroll
    for (int j = 0; j < 8; ++j){
      const float4 av = *reinterpret_cast<const float4*>(&abuf[wid][4*j]);
      y0 = fmaf(av.x, hos[(4*j+0)*DD + lane], y0);
      y1 = fmaf(av.y, hos[(4*j+1)*DD + lane], y1);
      y2 = fmaf(av.z, hos[(4*j+2)*DD + lane], y2);
      y3 = fmaf(av.w, hos[(4*j+3)*DD + lane], y3);
    }
    __builtin_amdgcn_wave_barrier();
    const float y = (y0+y1)+(y2+y3);
    const float s = fmaxf(y, 0.f) + xc;
    const float mean = wave_sum64(s) * (1.f/DD);
    const float d0 = s - mean;
    const float var = wave_sum64(d0*d0) * (1.f/DD);
    const float o2 = d0 * rsqrtf(var + LN_EPS) * gam + bet;
    xout[ridx*DD + lane] = 0.5f*(o1 + o2);
  }
}

extern "C" void kernel_launch(void* const* d_in, const int* in_sizes, int n_in,
                              void* d_out, int out_size, void* d_ws, size_t ws_size,
                              hipStream_t stream)
{
  (void)in_sizes; (void)n_in; (void)out_size; (void)ws_size;
  const float* x0  = (const float*)d_in[0];
  const float* W1  = (const float*)d_in[1];
  const float* b1  = (const float*)d_in[2];
  const float* W2  = (const float*)d_in[3];
  const float* b2  = (const float*)d_in[4];
  const float* lng = (const float*)d_in[5];
  const float* lnb = (const float*)d_in[6];
  const float* clf = (const float*)d_in[7];
  const float* em  = (const float*)d_in[8];
  const float* hg  = (const float*)d_in[9];
  const float* hb  = (const float*)d_in[10];
  float* out = (float*)d_out;

  // workspace layout (floats): x ping buffer | assign | hf | ho   (~76 MB total)
  float* ws_x   = (float*)d_ws;
  float* assign = ws_x + (size_t)ROWS*DD;
  float* hf     = assign + (size_t)ROWS*EE;
  float* ho     = hf + (size_t)BB*EE*DD;

  for (int i = 0; i < 3; ++i){
    const float* xin = (i == 0) ? x0 : ws_x;
    float* xout = (i == 2) ? out : ws_x;
    k1_stgcn<<<2048, 256, 0, stream>>>(xin, W1 + i*DD*DD, b1 + i*DD,
                                       W2 + i*DD*DD, b2 + i*DD,
                                       lng + i*DD, lnb + i*DD, out);
    hipMemsetAsync(hf, 0, (size_t)BB*EE*DD*sizeof(float), stream);
    k2_hyper1<<<BB*CPB2, 256, 0, stream>>>(xin, clf, assign, hf);
    k3_edge<<<BB, 256, 0, stream>>>(hf, em, ho);
    k4_combine<<<BB*CPB4, 256, 0, stream>>>(xin, out, assign, ho, hg, hb, xout);
  }
}

// Round 3
// 547.923 us; speedup vs baseline: 2.3294x; 2.3294x over previous
//
#include <hip/hip_runtime.h>

#define BB 16
#define TT 12
#define NN 1024
#define DD 64
#define EE 32
#define MM (TT*NN)          // 12288 rows per batch
#define ROWS (BB*MM)        // 196608 total rows
#define CPB2 64             // blocks per batch for K2
#define CPB4 96             // blocks per batch for K4
#define LN_EPS 1e-5f

typedef __attribute__((ext_vector_type(8))) short short8;
typedef __attribute__((ext_vector_type(4))) float f32x4;
typedef __attribute__((ext_vector_type(4))) int   int4v;

__device__ __forceinline__ float wave_sum64(float v){
  #pragma unroll
  for (int off = 32; off; off >>= 1) v += __shfl_xor(v, off);
  return v;
}

// pack two f32 -> one dword of 2 bf16 (RNE), low = a, high = b
__device__ __forceinline__ int cvt2(float a, float b){
  int r;
  asm("v_cvt_pk_bf16_f32 %0, %1, %2" : "=v"(r) : "v"(a), "v"(b));
  return r;
}

// ---------------- K1: fused STGCN via bf16 MFMA ----------------
// u = 0.5*(x[t-1]+x[t]); g1=u@W1^T+b1; g2=u@W2^T+b2; h=relu(g1*g2)+g1; out1=LN(h+x)
// Wave owns a 16-row tile. W1+W2 resident as 16 bf16 fragments (64 VGPR).
__global__ __launch_bounds__(256, 1)
void k1_stgcn(const float* __restrict__ x,
              const float* __restrict__ W1, const float* __restrict__ b1,
              const float* __restrict__ W2, const float* __restrict__ b2,
              const float* __restrict__ lng, const float* __restrict__ lnb,
              float* __restrict__ out1)
{
  const int lane = threadIdx.x & 63;
  const int wid  = threadIdx.x >> 6;
  const int l15  = lane & 15;
  const int lg   = lane >> 4;      // 0..3
  const int k0   = lg * 8;         // k-chunk start within K=32

  // B fragments: bw[mat][ntile][kchunk]; B[k][n] = W[n][k], n = 16*nt + l15
  short8 bw[2][4][2];
  const float* Wm[2] = {W1, W2};
  #pragma unroll
  for (int m = 0; m < 2; ++m)
    #pragma unroll
    for (int nt = 0; nt < 4; ++nt)
      #pragma unroll
      for (int kc = 0; kc < 2; ++kc){
        const float* src = Wm[m] + (size_t)(16*nt + l15)*DD + 32*kc + k0;
        const float4 p0 = *reinterpret_cast<const float4*>(src);
        const float4 p1 = *reinterpret_cast<const float4*>(src + 4);
        int4v w;
        w.x = cvt2(p0.x, p0.y); w.y = cvt2(p0.z, p0.w);
        w.z = cvt2(p1.x, p1.y); w.w = cvt2(p1.z, p1.w);
        bw[m][nt][kc] = __builtin_bit_cast(short8, w);
      }

  float b1c[4], b2c[4], gamc[4], betc[4];
  #pragma unroll
  for (int nt = 0; nt < 4; ++nt){
    b1c[nt]  = b1[l15 + 16*nt];
    b2c[nt]  = b2[l15 + 16*nt];
    gamc[nt] = lng[l15 + 16*nt];
    betc[nt] = lnb[l15 + 16*nt];
  }

  const int ntile = ROWS / 16;                 // 12288
  for (int tile = blockIdx.x*4 + wid; tile < ntile; tile += gridDim.x*4){
    const int r0 = tile * 16;
    const int t  = (r0 >> 10) % TT;            // whole tile shares t (1024 rows per t)

    // A fragments: row = r0 + l15, k = 32*kc + k0 + j
    short8 af[2];
    const float* xrow = x + (size_t)(r0 + l15)*DD;
    #pragma unroll
    for (int kc = 0; kc < 2; ++kc){
      const float* pc = xrow + 32*kc + k0;
      float4 a0 = *reinterpret_cast<const float4*>(pc);
      float4 a1 = *reinterpret_cast<const float4*>(pc + 4);
      if (t > 0){
        const float* pp = pc - (size_t)NN*DD;
        const float4 q0 = *reinterpret_cast<const float4*>(pp);
        const float4 q1 = *reinterpret_cast<const float4*>(pp + 4);
        a0.x = 0.5f*(a0.x+q0.x); a0.y = 0.5f*(a0.y+q0.y);
        a0.z = 0.5f*(a0.z+q0.z); a0.w = 0.5f*(a0.w+q0.w);
        a1.x = 0.5f*(a1.x+q1.x); a1.y = 0.5f*(a1.y+q1.y);
        a1.z = 0.5f*(a1.z+q1.z); a1.w = 0.5f*(a1.w+q1.w);
      } else {
        a0.x *= 0.5f; a0.y *= 0.5f; a0.z *= 0.5f; a0.w *= 0.5f;
        a1.x *= 0.5f; a1.y *= 0.5f; a1.z *= 0.5f; a1.w *= 0.5f;
      }
      int4v w;
      w.x = cvt2(a0.x, a0.y); w.y = cvt2(a0.z, a0.w);
      w.z = cvt2(a1.x, a1.y); w.w = cvt2(a1.z, a1.w);
      af[kc] = __builtin_bit_cast(short8, w);
    }

    f32x4 acc[2][4];
    #pragma unroll
    for (int m = 0; m < 2; ++m)
      #pragma unroll
      for (int nt = 0; nt < 4; ++nt)
        acc[m][nt] = (f32x4){0.f, 0.f, 0.f, 0.f};

    #pragma unroll
    for (int kc = 0; kc < 2; ++kc){
      #pragma unroll
      for (int nt = 0; nt < 4; ++nt){
        acc[0][nt] = __builtin_amdgcn_mfma_f32_16x16x32_bf16(af[kc], bw[0][nt][kc], acc[0][nt], 0, 0, 0);
        acc[1][nt] = __builtin_amdgcn_mfma_f32_16x16x32_bf16(af[kc], bw[1][nt][kc], acc[1][nt], 0, 0, 0);
      }
    }

    // epilogue in C/D layout: col = l15 + 16*nt, row = r0 + 4*lg + q
    #pragma unroll
    for (int q = 0; q < 4; ++q){
      const int row = r0 + 4*lg + q;
      float s[4];
      float rs = 0.f;
      #pragma unroll
      for (int nt = 0; nt < 4; ++nt){
        const float xr = x[(size_t)row*DD + l15 + 16*nt];
        const float g1 = acc[0][nt][q] + b1c[nt];
        const float g2 = acc[1][nt][q] + b2c[nt];
        const float h  = fmaxf(g1*g2, 0.f) + g1;
        s[nt] = h + xr;
        rs += s[nt];
      }
      #pragma unroll
      for (int off = 8; off; off >>= 1) rs += __shfl_xor(rs, off);
      const float mean = rs * (1.f/DD);
      float d[4]; float vs = 0.f;
      #pragma unroll
      for (int nt = 0; nt < 4; ++nt){ d[nt] = s[nt] - mean; vs = fmaf(d[nt], d[nt], vs); }
      #pragma unroll
      for (int off = 8; off; off >>= 1) vs += __shfl_xor(vs, off);
      const float inv = rsqrtf(vs * (1.f/DD) + LN_EPS);
      #pragma unroll
      for (int nt = 0; nt < 4; ++nt)
        out1[(size_t)row*DD + l15 + 16*nt] = d[nt]*inv*gamc[nt] + betc[nt];
    }
  }
}

// ---------------- K2: assign = softmax(x @ edge_clf); hf[b,e,d] += a[m,e]*x[m,d] ----------------
__global__ __launch_bounds__(256, 2)
void k2_hyper1(const float* __restrict__ x, const float* __restrict__ clf,
               float* __restrict__ assign_ws, float* __restrict__ hf)
{
  __shared__ __align__(16) float xbuf[4][DD];
  __shared__ __align__(16) float abuf[4][EE];
  __shared__ __align__(16) float red[4][EE][DD];   // 32 KB: block-level hf reduce
  const int lane = threadIdx.x & 63;
  const int wid  = threadIdx.x >> 6;
  const int b = blockIdx.x / CPB2;
  const int chunk = blockIdx.x % CPB2;
  const int e = lane & 31;
  const int half = lane >> 5;

  float clfreg[EE];
  #pragma unroll
  for (int j = 0; j < EE; ++j) clfreg[j] = clf[(half*32 + j)*EE + e];

  float hfacc[EE];
  #pragma unroll
  for (int j = 0; j < EE; ++j) hfacc[j] = 0.f;

  const int rpw = (MM / CPB2) / 4;   // 48 rows per wave
  for (int it = 0; it < rpw; ++it){
    const int mrow = chunk*(MM/CPB2) + wid*rpw + it;
    const size_t ridx = (size_t)b*MM + mrow;
    const float xv = x[ridx*DD + lane];
    xbuf[wid][lane] = xv;
    __builtin_amdgcn_wave_barrier();
    float pt[4] = {0.f,0.f,0.f,0.f};
    #pragma unroll
    for (int j = 0; j < 8; ++j){
      const float4 uv = *reinterpret_cast<const float4*>(&xbuf[wid][half*32 + 4*j]);
      pt[0] = fmaf(uv.x, clfreg[4*j+0], pt[0]);
      pt[1] = fmaf(uv.y, clfreg[4*j+1], pt[1]);
      pt[2] = fmaf(uv.z, clfreg[4*j+2], pt[2]);
      pt[3] = fmaf(uv.w, clfreg[4*j+3], pt[3]);
    }
    const float part = (pt[0]+pt[1]) + (pt[2]+pt[3]);
    const float logit = part + __shfl_xor(part, 32);
    float mx = logit;
    #pragma unroll
    for (int off = 16; off; off >>= 1) mx = fmaxf(mx, __shfl_xor(mx, off));
    const float ex = expf(logit - mx);
    float sm = ex;
    #pragma unroll
    for (int off = 16; off; off >>= 1) sm += __shfl_xor(sm, off);
    const float a = ex / sm;
    if (half == 0) assign_ws[ridx*EE + e] = a;
    abuf[wid][e] = a;
    __builtin_amdgcn_wave_barrier();
    #pragma unroll
    for (int j = 0; j < 8; ++j){
      const float4 av = *reinterpret_cast<const float4*>(&abuf[wid][4*j]);
      hfacc[4*j+0] = fmaf(av.x, xv, hfacc[4*j+0]);
      hfacc[4*j+1] = fmaf(av.y, xv, hfacc[4*j+1]);
      hfacc[4*j+2] = fmaf(av.z, xv, hfacc[4*j+2]);
      hfacc[4*j+3] = fmaf(av.w, xv, hfacc[4*j+3]);
    }
    __builtin_amdgcn_wave_barrier();
  }
  // block-level reduce across 4 waves, then one atomic per element per block
  #pragma unroll
  for (int j = 0; j < EE; ++j) red[wid][j][lane] = hfacc[j];
  __syncthreads();
  const float* rf = &red[0][0][0];
  for (int k = threadIdx.x; k < EE*DD; k += 256){
    const float s = (rf[k] + rf[EE*DD + k]) + (rf[2*EE*DD + k] + rf[3*EE*DD + k]);
    atomicAdd(&hf[(size_t)b*EE*DD + k], s);
  }
}

// ---------------- K3: hyper_out = relu(edge_map @ hf) + hf ----------------
__global__ void k3_edge(const float* __restrict__ hf, const float* __restrict__ em,
                        float* __restrict__ ho)
{
  __shared__ float ems[EE*EE];
  __shared__ float hfs[EE*DD];
  const int b = blockIdx.x;
  const int tid = threadIdx.x;
  for (int i = tid; i < EE*EE; i += 256) ems[i] = em[i];
  for (int i = tid; i < EE*DD; i += 256) hfs[i] = hf[(size_t)b*EE*DD + i];
  __syncthreads();
  for (int i = tid; i < EE*DD; i += 256){
    const int e = i >> 6, d = i & 63;
    float acc = 0.f;
    #pragma unroll
    for (int f = 0; f < EE; ++f) acc = fmaf(ems[e*EE+f], hfs[f*DD+d], acc);
    ho[(size_t)b*EE*DD + i] = fmaxf(acc, 0.f) + hfs[e*DD+d];
  }
}

// ---------------- K4: y = relu(assign @ hyper_out); out2 = LN(y+x); xout = 0.5*(out1+out2) ----------------
__global__ __launch_bounds__(256, 4)
void k4_combine(const float* __restrict__ x, const float* __restrict__ out1,
                const float* __restrict__ assign_ws, const float* __restrict__ ho,
                const float* __restrict__ hg, const float* __restrict__ hb,
                float* __restrict__ xout)
{
  __shared__ __align__(16) float hos[EE*DD];
  __shared__ __align__(16) float abuf[4][EE];
  const int lane = threadIdx.x & 63;
  const int wid  = threadIdx.x >> 6;
  const int b = blockIdx.x / CPB4;
  const int chunk = blockIdx.x % CPB4;
  for (int i = threadIdx.x; i < EE*DD; i += 256) hos[i] = ho[(size_t)b*EE*DD + i];
  __syncthreads();
  const float gam = hg[lane], bet = hb[lane];
  const int rpw = (MM / CPB4) / 4;   // 32 rows per wave
  for (int it = 0; it < rpw; ++it){
    const int mrow = chunk*(MM/CPB4) + wid*rpw + it;
    const size_t ridx = (size_t)b*MM + mrow;
    const float xc = x[ridx*DD + lane];
    const float o1 = out1[ridx*DD + lane];
    if (lane < EE) abuf[wid][lane] = assign_ws[ridx*EE + lane];
    __builtin_amdgcn_wave_barrier();
    float y0=0.f, y1=0.f, y2=0.f, y3=0.f;
    #pragma unroll
    for (int j = 0; j < 8; ++j){
      const float4 av = *reinterpret_cast<const float4*>(&abuf[wid][4*j]);
      y0 = fmaf(av.x, hos[(4*j+0)*DD + lane], y0);
      y1 = fmaf(av.y, hos[(4*j+1)*DD + lane], y1);
      y2 = fmaf(av.z, hos[(4*j+2)*DD + lane], y2);
      y3 = fmaf(av.w, hos[(4*j+3)*DD + lane], y3);
    }
    __builtin_amdgcn_wave_barrier();
    const float y = (y0+y1)+(y2+y3);
    const float s = fmaxf(y, 0.f) + xc;
    const float mean = wave_sum64(s) * (1.f/DD);
    const float d0 = s - mean;
    const float var = wave_sum64(d0*d0) * (1.f/DD);
    const float o2 = d0 * rsqrtf(var + LN_EPS) * gam + bet;
    xout[ridx*DD + lane] = 0.5f*(o1 + o2);
  }
}

extern "C" void kernel_launch(void* const* d_in, const int* in_sizes, int n_in,
                              void* d_out, int out_size, void* d_ws, size_t ws_size,
                              hipStream_t stream)
{
  (void)in_sizes; (void)n_in; (void)out_size; (void)ws_size;
  const float* x0  = (const float*)d_in[0];
  const float* W1  = (const float*)d_in[1];
  const float* b1  = (const float*)d_in[2];
  const float* W2  = (const float*)d_in[3];
  const float* b2  = (const float*)d_in[4];
  const float* lng = (const float*)d_in[5];
  const float* lnb = (const float*)d_in[6];
  const float* clf = (const float*)d_in[7];
  const float* em  = (const float*)d_in[8];
  const float* hg  = (const float*)d_in[9];
  const float* hb  = (const float*)d_in[10];
  float* out = (float*)d_out;

  // workspace layout (floats): x ping buffer | assign | hf | ho
  float* ws_x   = (float*)d_ws;
  float* assign = ws_x + (size_t)ROWS*DD;
  float* hf     = assign + (size_t)ROWS*EE;
  float* ho     = hf + (size_t)BB*EE*DD;

  for (int i = 0; i < 3; ++i){
    const float* xin = (i == 0) ? x0 : ws_x;
    float* xout = (i == 2) ? out : ws_x;
    k1_stgcn<<<1536, 256, 0, stream>>>(xin, W1 + i*DD*DD, b1 + i*DD,
                                       W2 + i*DD*DD, b2 + i*DD,
                                       lng + i*DD, lnb + i*DD, out);
    hipMemsetAsync(hf, 0, (size_t)BB*EE*DD*sizeof(float), stream);
    k2_hyper1<<<BB*CPB2, 256, 0, stream>>>(xin, clf, assign, hf);
    k3_edge<<<BB, 256, 0, stream>>>(hf, em, ho);
    k4_combine<<<BB*CPB4, 256, 0, stream>>>(xin, out, assign, ho, hg, hb, xout);
  }
}

// Round 6
// 424.316 us; speedup vs baseline: 3.0080x; 1.2913x over previous
//
#include <hip/hip_runtime.h>

#define BB 16
#define TT 12
#define NN 1024
#define DD 64
#define EE 32
#define MM (TT*NN)          // 12288 rows per batch
#define ROWS (BB*MM)        // 196608 total rows
#define CPB2 64             // blocks per batch for K2
#define CPB4 48             // blocks per batch for K4
#define LN_EPS 1e-5f

typedef __attribute__((ext_vector_type(8))) short short8;
typedef __attribute__((ext_vector_type(4))) float f32x4;
typedef __attribute__((ext_vector_type(4))) int   int4v;

__device__ __forceinline__ float wave_sum64(float v){
  #pragma unroll
  for (int off = 32; off; off >>= 1) v += __shfl_xor(v, off);
  return v;
}

// pack two f32 -> one dword of 2 bf16 (RNE), low = a, high = b
__device__ __forceinline__ int cvt2(float a, float b){
  int r;
  asm("v_cvt_pk_bf16_f32 %0, %1, %2" : "=v"(r) : "v"(a), "v"(b));
  return r;
}
__device__ __forceinline__ unsigned short bf16of(float a){
  return (unsigned short)(cvt2(a, a) & 0xffff);
}
__device__ __forceinline__ float f32of(unsigned short h){
  const unsigned int u = ((unsigned int)h) << 16;
  return __builtin_bit_cast(float, u);
}

// ---------------- K1: fused STGCN via bf16 MFMA ----------------
__global__ __launch_bounds__(256, 1)
void k1_stgcn(const float* __restrict__ x,
              const float* __restrict__ W1, const float* __restrict__ b1,
              const float* __restrict__ W2, const float* __restrict__ b2,
              const float* __restrict__ lng, const float* __restrict__ lnb,
              float* __restrict__ out1)
{
  const int lane = threadIdx.x & 63;
  const int wid  = threadIdx.x >> 6;
  const int l15  = lane & 15;
  const int lg   = lane >> 4;      // 0..3
  const int k0   = lg * 8;         // k-chunk start within K=32

  short8 bw[2][4][2];
  const float* Wm[2] = {W1, W2};
  #pragma unroll
  for (int m = 0; m < 2; ++m)
    #pragma unroll
    for (int nt = 0; nt < 4; ++nt)
      #pragma unroll
      for (int kc = 0; kc < 2; ++kc){
        const float* src = Wm[m] + (size_t)(16*nt + l15)*DD + 32*kc + k0;
        const float4 p0 = *reinterpret_cast<const float4*>(src);
        const float4 p1 = *reinterpret_cast<const float4*>(src + 4);
        int4v w;
        w.x = cvt2(p0.x, p0.y); w.y = cvt2(p0.z, p0.w);
        w.z = cvt2(p1.x, p1.y); w.w = cvt2(p1.z, p1.w);
        bw[m][nt][kc] = __builtin_bit_cast(short8, w);
      }

  float b1c[4], b2c[4], gamc[4], betc[4];
  #pragma unroll
  for (int nt = 0; nt < 4; ++nt){
    b1c[nt]  = b1[l15 + 16*nt];
    b2c[nt]  = b2[l15 + 16*nt];
    gamc[nt] = lng[l15 + 16*nt];
    betc[nt] = lnb[l15 + 16*nt];
  }

  const int ntile = ROWS / 16;                 // 12288
  for (int tile = blockIdx.x*4 + wid; tile < ntile; tile += gridDim.x*4){
    const int r0 = tile * 16;
    const int t  = (r0 >> 10) % TT;            // whole tile shares t

    short8 af[2];
    const float* xrow = x + (size_t)(r0 + l15)*DD;
    #pragma unroll
    for (int kc = 0; kc < 2; ++kc){
      const float* pc = xrow + 32*kc + k0;
      float4 a0 = *reinterpret_cast<const float4*>(pc);
      float4 a1 = *reinterpret_cast<const float4*>(pc + 4);
      if (t > 0){
        const float* pp = pc - (size_t)NN*DD;
        const float4 q0 = *reinterpret_cast<const float4*>(pp);
        const float4 q1 = *reinterpret_cast<const float4*>(pp + 4);
        a0.x = 0.5f*(a0.x+q0.x); a0.y = 0.5f*(a0.y+q0.y);
        a0.z = 0.5f*(a0.z+q0.z); a0.w = 0.5f*(a0.w+q0.w);
        a1.x = 0.5f*(a1.x+q1.x); a1.y = 0.5f*(a1.y+q1.y);
        a1.z = 0.5f*(a1.z+q1.z); a1.w = 0.5f*(a1.w+q1.w);
      } else {
        a0.x *= 0.5f; a0.y *= 0.5f; a0.z *= 0.5f; a0.w *= 0.5f;
        a1.x *= 0.5f; a1.y *= 0.5f; a1.z *= 0.5f; a1.w *= 0.5f;
      }
      int4v w;
      w.x = cvt2(a0.x, a0.y); w.y = cvt2(a0.z, a0.w);
      w.z = cvt2(a1.x, a1.y); w.w = cvt2(a1.z, a1.w);
      af[kc] = __builtin_bit_cast(short8, w);
    }

    f32x4 acc[2][4];
    #pragma unroll
    for (int m = 0; m < 2; ++m)
      #pragma unroll
      for (int nt = 0; nt < 4; ++nt)
        acc[m][nt] = (f32x4){0.f, 0.f, 0.f, 0.f};

    #pragma unroll
    for (int kc = 0; kc < 2; ++kc){
      #pragma unroll
      for (int nt = 0; nt < 4; ++nt){
        acc[0][nt] = __builtin_amdgcn_mfma_f32_16x16x32_bf16(af[kc], bw[0][nt][kc], acc[0][nt], 0, 0, 0);
        acc[1][nt] = __builtin_amdgcn_mfma_f32_16x16x32_bf16(af[kc], bw[1][nt][kc], acc[1][nt], 0, 0, 0);
      }
    }

    #pragma unroll
    for (int q = 0; q < 4; ++q){
      const int row = r0 + 4*lg + q;
      float s[4];
      float rs = 0.f;
      #pragma unroll
      for (int nt = 0; nt < 4; ++nt){
        const float xr = x[(size_t)row*DD + l15 + 16*nt];
        const float g1 = acc[0][nt][q] + b1c[nt];
        const float g2 = acc[1][nt][q] + b2c[nt];
        const float h  = fmaxf(g1*g2, 0.f) + g1;
        s[nt] = h + xr;
        rs += s[nt];
      }
      #pragma unroll
      for (int off = 8; off; off >>= 1) rs += __shfl_xor(rs, off);
      const float mean = rs * (1.f/DD);
      float d[4]; float vs = 0.f;
      #pragma unroll
      for (int nt = 0; nt < 4; ++nt){ d[nt] = s[nt] - mean; vs = fmaf(d[nt], d[nt], vs); }
      #pragma unroll
      for (int off = 8; off; off >>= 1) vs += __shfl_xor(vs, off);
      const float inv = rsqrtf(vs * (1.f/DD) + LN_EPS);
      #pragma unroll
      for (int nt = 0; nt < 4; ++nt)
        out1[(size_t)row*DD + l15 + 16*nt] = d[nt]*inv*gamc[nt] + betc[nt];
    }
  }
}

// ---------------- K2: assign hi/lo (bf16) = softmax(x @ edge_clf); hf[b,e,d] += a[m,e]*x[m,d] ----------------
__global__ __launch_bounds__(256, 2)
void k2_hyper1(const float* __restrict__ x, const float* __restrict__ clf,
               unsigned short* __restrict__ assign_hi, unsigned short* __restrict__ assign_lo,
               float* __restrict__ hf)
{
  __shared__ __align__(16) float xbuf[4][DD];
  __shared__ __align__(16) float abuf[4][EE];
  __shared__ __align__(16) float red[4][EE][DD];
  const int lane = threadIdx.x & 63;
  const int wid  = threadIdx.x >> 6;
  const int b = blockIdx.x / CPB2;
  const int chunk = blockIdx.x % CPB2;
  const int e = lane & 31;
  const int half = lane >> 5;

  float clfreg[EE];
  #pragma unroll
  for (int j = 0; j < EE; ++j) clfreg[j] = clf[(half*32 + j)*EE + e];

  float hfacc[EE];
  #pragma unroll
  for (int j = 0; j < EE; ++j) hfacc[j] = 0.f;

  const int rpw = (MM / CPB2) / 4;   // 48 rows per wave
  for (int it = 0; it < rpw; ++it){
    const int mrow = chunk*(MM/CPB2) + wid*rpw + it;
    const size_t ridx = (size_t)b*MM + mrow;
    const float xv = x[ridx*DD + lane];
    xbuf[wid][lane] = xv;
    __builtin_amdgcn_wave_barrier();
    float pt[4] = {0.f,0.f,0.f,0.f};
    #pragma unroll
    for (int j = 0; j < 8; ++j){
      const float4 uv = *reinterpret_cast<const float4*>(&xbuf[wid][half*32 + 4*j]);
      pt[0] = fmaf(uv.x, clfreg[4*j+0], pt[0]);
      pt[1] = fmaf(uv.y, clfreg[4*j+1], pt[1]);
      pt[2] = fmaf(uv.z, clfreg[4*j+2], pt[2]);
      pt[3] = fmaf(uv.w, clfreg[4*j+3], pt[3]);
    }
    const float part = (pt[0]+pt[1]) + (pt[2]+pt[3]);
    const float logit = part + __shfl_xor(part, 32);
    float mx = logit;
    #pragma unroll
    for (int off = 16; off; off >>= 1) mx = fmaxf(mx, __shfl_xor(mx, off));
    const float ex = expf(logit - mx);
    float sm = ex;
    #pragma unroll
    for (int off = 16; off; off >>= 1) sm += __shfl_xor(sm, off);
    const float a = ex / sm;
    if (half == 0){
      const unsigned short hi = bf16of(a);
      assign_hi[ridx*EE + e] = hi;
      assign_lo[ridx*EE + e] = bf16of(a - f32of(hi));
    }
    abuf[wid][e] = a;
    __builtin_amdgcn_wave_barrier();
    #pragma unroll
    for (int j = 0; j < 8; ++j){
      const float4 av = *reinterpret_cast<const float4*>(&abuf[wid][4*j]);
      hfacc[4*j+0] = fmaf(av.x, xv, hfacc[4*j+0]);
      hfacc[4*j+1] = fmaf(av.y, xv, hfacc[4*j+1]);
      hfacc[4*j+2] = fmaf(av.z, xv, hfacc[4*j+2]);
      hfacc[4*j+3] = fmaf(av.w, xv, hfacc[4*j+3]);
    }
    __builtin_amdgcn_wave_barrier();
  }
  #pragma unroll
  for (int j = 0; j < EE; ++j) red[wid][j][lane] = hfacc[j];
  __syncthreads();
  const float* rf = &red[0][0][0];
  for (int k = threadIdx.x; k < EE*DD; k += 256){
    const float s = (rf[k] + rf[EE*DD + k]) + (rf[2*EE*DD + k] + rf[3*EE*DD + k]);
    atomicAdd(&hf[(size_t)b*EE*DD + k], s);
  }
}

// ---------------- K3: ho = relu(edge_map @ hf) + hf; emit transposed bf16 hi/lo [d][e] ----------------
__global__ void k3_edge(const float* __restrict__ hf, const float* __restrict__ em,
                        unsigned short* __restrict__ ho_hi, unsigned short* __restrict__ ho_lo)
{
  __shared__ float ems[EE*EE];
  __shared__ float hfs[EE*DD];
  const int b = blockIdx.x;
  const int tid = threadIdx.x;
  for (int i = tid; i < EE*EE; i += 256) ems[i] = em[i];
  for (int i = tid; i < EE*DD; i += 256) hfs[i] = hf[(size_t)b*EE*DD + i];
  __syncthreads();
  for (int i = tid; i < EE*DD; i += 256){
    const int e = i >> 6, d = i & 63;
    float acc = 0.f;
    #pragma unroll
    for (int f = 0; f < EE; ++f) acc = fmaf(ems[e*EE+f], hfs[f*DD+d], acc);
    const float v = fmaxf(acc, 0.f) + hfs[e*DD+d];
    const unsigned short hi = bf16of(v);
    const unsigned short lo = bf16of(v - f32of(hi));
    ho_hi[((size_t)b*DD + d)*EE + e] = hi;
    ho_lo[((size_t)b*DD + d)*EE + e] = lo;
  }
}

// ---------------- K4: y = relu(assign @ ho) via split-MFMA; out2 = LN(y+x); xout = 0.5*(out1+out2) ----------------
__global__ __launch_bounds__(256, 4)
void k4_combine(const float* __restrict__ x, const float* __restrict__ out1,
                const unsigned short* __restrict__ assign_hi,
                const unsigned short* __restrict__ assign_lo,
                const unsigned short* __restrict__ ho_hi,
                const unsigned short* __restrict__ ho_lo,
                const float* __restrict__ hg, const float* __restrict__ hb,
                float* __restrict__ xout)
{
  const int lane = threadIdx.x & 63;
  const int wid  = threadIdx.x >> 6;
  const int b    = blockIdx.x / CPB4;
  const int blk  = blockIdx.x % CPB4;
  const int l15  = lane & 15;
  const int lg   = lane >> 4;

  short8 bwh[4], bwl[4];
  #pragma unroll
  for (int nt = 0; nt < 4; ++nt){
    const size_t off = ((size_t)b*DD + l15 + 16*nt)*EE + 8*lg;
    bwh[nt] = *reinterpret_cast<const short8*>(ho_hi + off);
    bwl[nt] = *reinterpret_cast<const short8*>(ho_lo + off);
  }

  float gamc[4], betc[4];
  #pragma unroll
  for (int nt = 0; nt < 4; ++nt){
    gamc[nt] = hg[l15 + 16*nt];
    betc[nt] = hb[l15 + 16*nt];
  }

  const int tpb = MM / 16;              // 768 tiles per batch
  for (int tl = blk*4 + wid; tl < tpb; tl += CPB4*4){
    const size_t r0 = (size_t)b*MM + tl*16;

    const short8 afh = *reinterpret_cast<const short8*>(assign_hi + (r0 + l15)*EE + 8*lg);
    const short8 afl = *reinterpret_cast<const short8*>(assign_lo + (r0 + l15)*EE + 8*lg);

    f32x4 acc[4];
    #pragma unroll
    for (int nt = 0; nt < 4; ++nt) acc[nt] = (f32x4){0.f,0.f,0.f,0.f};
    #pragma unroll
    for (int nt = 0; nt < 4; ++nt){
      acc[nt] = __builtin_amdgcn_mfma_f32_16x16x32_bf16(afh, bwh[nt], acc[nt], 0, 0, 0);
      acc[nt] = __builtin_amdgcn_mfma_f32_16x16x32_bf16(afh, bwl[nt], acc[nt], 0, 0, 0);
      acc[nt] = __builtin_amdgcn_mfma_f32_16x16x32_bf16(afl, bwh[nt], acc[nt], 0, 0, 0);
    }

    #pragma unroll
    for (int q = 0; q < 4; ++q){
      const size_t row = r0 + 4*lg + q;
      float s[4];
      float rs = 0.f;
      #pragma unroll
      for (int nt = 0; nt < 4; ++nt){
        const float xr = x[row*DD + l15 + 16*nt];
        s[nt] = fmaxf(acc[nt][q], 0.f) + xr;
        rs += s[nt];
      }
      #pragma unroll
      for (int off = 8; off; off >>= 1) rs += __shfl_xor(rs, off);
      const float mean = rs * (1.f/DD);
      float d[4]; float vs = 0.f;
      #pragma unroll
      for (int nt = 0; nt < 4; ++nt){ d[nt] = s[nt] - mean; vs = fmaf(d[nt], d[nt], vs); }
      #pragma unroll
      for (int off = 8; off; off >>= 1) vs += __shfl_xor(vs, off);
      const float inv = rsqrtf(vs * (1.f/DD) + LN_EPS);
      #pragma unroll
      for (int nt = 0; nt < 4; ++nt){
        const float o2 = d[nt]*inv*gamc[nt] + betc[nt];
        const float o1 = out1[row*DD + l15 + 16*nt];
        xout[row*DD + l15 + 16*nt] = 0.5f*(o1 + o2);
      }
    }
  }
}

extern "C" void kernel_launch(void* const* d_in, const int* in_sizes, int n_in,
                              void* d_out, int out_size, void* d_ws, size_t ws_size,
                              hipStream_t stream)
{
  (void)in_sizes; (void)n_in; (void)out_size; (void)ws_size;
  const float* x0  = (const float*)d_in[0];
  const float* W1  = (const float*)d_in[1];
  const float* b1  = (const float*)d_in[2];
  const float* W2  = (const float*)d_in[3];
  const float* b2  = (const float*)d_in[4];
  const float* lng = (const float*)d_in[5];
  const float* lnb = (const float*)d_in[6];
  const float* clf = (const float*)d_in[7];
  const float* em  = (const float*)d_in[8];
  const float* hg  = (const float*)d_in[9];
  const float* hb  = (const float*)d_in[10];
  float* out = (float*)d_out;

  // workspace: x ping (fp32) | hf (fp32) | assign hi/lo bf16 | ho hi/lo bf16
  float* ws_x = (float*)d_ws;
  float* hf   = ws_x + (size_t)ROWS*DD;
  unsigned short* assign_hi = (unsigned short*)(hf + (size_t)BB*EE*DD);
  unsigned short* assign_lo = assign_hi + (size_t)ROWS*EE;
  unsigned short* ho_hi     = assign_lo + (size_t)ROWS*EE;
  unsigned short* ho_lo     = ho_hi + (size_t)BB*DD*EE;

  for (int i = 0; i < 3; ++i){
    const float* xin = (i == 0) ? x0 : ws_x;
    float* xout = (i == 2) ? out : ws_x;
    k1_stgcn<<<1536, 256, 0, stream>>>(xin, W1 + i*DD*DD, b1 + i*DD,
                                       W2 + i*DD*DD, b2 + i*DD,
                                       lng + i*DD, lnb + i*DD, out);
    hipMemsetAsync(hf, 0, (size_t)BB*EE*DD*sizeof(float), stream);
    k2_hyper1<<<BB*CPB2, 256, 0, stream>>>(xin, clf, assign_hi, assign_lo, hf);
    k3_edge<<<BB, 256, 0, stream>>>(hf, em, ho_hi, ho_lo);
    k4_combine<<<BB*CPB4, 256, 0, stream>>>(xin, out, assign_hi, assign_lo, ho_hi, ho_lo, hg, hb, xout);
  }
}

// Round 7
// 395.239 us; speedup vs baseline: 3.2293x; 1.0736x over previous
//
#include <hip/hip_runtime.h>

#define BB 16
#define TT 12
#define NN 1024
#define DD 64
#define EE 32
#define MM (TT*NN)          // 12288 rows per batch
#define ROWS (BB*MM)        // 196608 total rows
#define CPB2N 48            // k2 blocks per batch (192 waves/batch, 2 chunks of 32 rows each)
#define CPB4 48             // k4 blocks per batch
#define LN_EPS 1e-5f

typedef __attribute__((ext_vector_type(8))) short short8;
typedef __attribute__((ext_vector_type(4))) float f32x4;
typedef __attribute__((ext_vector_type(4))) int   int4v;

// pack two f32 -> one dword of 2 bf16 (RNE), low = a, high = b
__device__ __forceinline__ int cvt2(float a, float b){
  int r;
  asm("v_cvt_pk_bf16_f32 %0, %1, %2" : "=v"(r) : "v"(a), "v"(b));
  return r;
}
__device__ __forceinline__ unsigned short bf16of(float a){
  return (unsigned short)(cvt2(a, a) & 0xffff);
}
__device__ __forceinline__ float f32of(unsigned short h){
  return __builtin_bit_cast(float, (unsigned int)h << 16);
}
__device__ __forceinline__ float lo16f(int w){ return __builtin_bit_cast(float, (unsigned int)w << 16); }
__device__ __forceinline__ float hi16f(int w){ return __builtin_bit_cast(float, (unsigned int)w & 0xffff0000u); }

__device__ __forceinline__ short8 pack_hi8(const float* v){
  int4v w;
  w.x = cvt2(v[0], v[1]); w.y = cvt2(v[2], v[3]);
  w.z = cvt2(v[4], v[5]); w.w = cvt2(v[6], v[7]);
  return __builtin_bit_cast(short8, w);
}
__device__ __forceinline__ short8 pack_lo8(const float* v, short8 hi){
  const int4v wh = __builtin_bit_cast(int4v, hi);
  float r[8];
  r[0] = v[0] - lo16f(wh.x); r[1] = v[1] - hi16f(wh.x);
  r[2] = v[2] - lo16f(wh.y); r[3] = v[3] - hi16f(wh.y);
  r[4] = v[4] - lo16f(wh.z); r[5] = v[5] - hi16f(wh.z);
  r[6] = v[6] - lo16f(wh.w); r[7] = v[7] - hi16f(wh.w);
  return pack_hi8(r);
}

// ---------------- K1: fused STGCN via bf16 MFMA (unchanged from round 6) ----------------
__global__ __launch_bounds__(256, 1)
void k1_stgcn(const float* __restrict__ x,
              const float* __restrict__ W1, const float* __restrict__ b1,
              const float* __restrict__ W2, const float* __restrict__ b2,
              const float* __restrict__ lng, const float* __restrict__ lnb,
              float* __restrict__ out1)
{
  const int lane = threadIdx.x & 63;
  const int wid  = threadIdx.x >> 6;
  const int l15  = lane & 15;
  const int lg   = lane >> 4;
  const int k0   = lg * 8;

  short8 bw[2][4][2];
  const float* Wm[2] = {W1, W2};
  #pragma unroll
  for (int m = 0; m < 2; ++m)
    #pragma unroll
    for (int nt = 0; nt < 4; ++nt)
      #pragma unroll
      for (int kc = 0; kc < 2; ++kc){
        const float* src = Wm[m] + (size_t)(16*nt + l15)*DD + 32*kc + k0;
        const float4 p0 = *reinterpret_cast<const float4*>(src);
        const float4 p1 = *reinterpret_cast<const float4*>(src + 4);
        int4v w;
        w.x = cvt2(p0.x, p0.y); w.y = cvt2(p0.z, p0.w);
        w.z = cvt2(p1.x, p1.y); w.w = cvt2(p1.z, p1.w);
        bw[m][nt][kc] = __builtin_bit_cast(short8, w);
      }

  float b1c[4], b2c[4], gamc[4], betc[4];
  #pragma unroll
  for (int nt = 0; nt < 4; ++nt){
    b1c[nt]  = b1[l15 + 16*nt];
    b2c[nt]  = b2[l15 + 16*nt];
    gamc[nt] = lng[l15 + 16*nt];
    betc[nt] = lnb[l15 + 16*nt];
  }

  const int ntile = ROWS / 16;
  for (int tile = blockIdx.x*4 + wid; tile < ntile; tile += gridDim.x*4){
    const int r0 = tile * 16;
    const int t  = (r0 >> 10) % TT;

    short8 af[2];
    const float* xrow = x + (size_t)(r0 + l15)*DD;
    #pragma unroll
    for (int kc = 0; kc < 2; ++kc){
      const float* pc = xrow + 32*kc + k0;
      float4 a0 = *reinterpret_cast<const float4*>(pc);
      float4 a1 = *reinterpret_cast<const float4*>(pc + 4);
      if (t > 0){
        const float* pp = pc - (size_t)NN*DD;
        const float4 q0 = *reinterpret_cast<const float4*>(pp);
        const float4 q1 = *reinterpret_cast<const float4*>(pp + 4);
        a0.x = 0.5f*(a0.x+q0.x); a0.y = 0.5f*(a0.y+q0.y);
        a0.z = 0.5f*(a0.z+q0.z); a0.w = 0.5f*(a0.w+q0.w);
        a1.x = 0.5f*(a1.x+q1.x); a1.y = 0.5f*(a1.y+q1.y);
        a1.z = 0.5f*(a1.z+q1.z); a1.w = 0.5f*(a1.w+q1.w);
      } else {
        a0.x *= 0.5f; a0.y *= 0.5f; a0.z *= 0.5f; a0.w *= 0.5f;
        a1.x *= 0.5f; a1.y *= 0.5f; a1.z *= 0.5f; a1.w *= 0.5f;
      }
      int4v w;
      w.x = cvt2(a0.x, a0.y); w.y = cvt2(a0.z, a0.w);
      w.z = cvt2(a1.x, a1.y); w.w = cvt2(a1.z, a1.w);
      af[kc] = __builtin_bit_cast(short8, w);
    }

    f32x4 acc[2][4];
    #pragma unroll
    for (int m = 0; m < 2; ++m)
      #pragma unroll
      for (int nt = 0; nt < 4; ++nt)
        acc[m][nt] = (f32x4){0.f, 0.f, 0.f, 0.f};

    #pragma unroll
    for (int kc = 0; kc < 2; ++kc){
      #pragma unroll
      for (int nt = 0; nt < 4; ++nt){
        acc[0][nt] = __builtin_amdgcn_mfma_f32_16x16x32_bf16(af[kc], bw[0][nt][kc], acc[0][nt], 0, 0, 0);
        acc[1][nt] = __builtin_amdgcn_mfma_f32_16x16x32_bf16(af[kc], bw[1][nt][kc], acc[1][nt], 0, 0, 0);
      }
    }

    #pragma unroll
    for (int q = 0; q < 4; ++q){
      const int row = r0 + 4*lg + q;
      float s[4];
      float rs = 0.f;
      #pragma unroll
      for (int nt = 0; nt < 4; ++nt){
        const float xr = x[(size_t)row*DD + l15 + 16*nt];
        const float g1 = acc[0][nt][q] + b1c[nt];
        const float g2 = acc[1][nt][q] + b2c[nt];
        const float h  = fmaxf(g1*g2, 0.f) + g1;
        s[nt] = h + xr;
        rs += s[nt];
      }
      #pragma unroll
      for (int off = 8; off; off >>= 1) rs += __shfl_xor(rs, off);
      const float mean = rs * (1.f/DD);
      float d[4]; float vs = 0.f;
      #pragma unroll
      for (int nt = 0; nt < 4; ++nt){ d[nt] = s[nt] - mean; vs = fmaf(d[nt], d[nt], vs); }
      #pragma unroll
      for (int off = 8; off; off >>= 1) vs += __shfl_xor(vs, off);
      const float inv = rsqrtf(vs * (1.f/DD) + LN_EPS);
      #pragma unroll
      for (int nt = 0; nt < 4; ++nt)
        out1[(size_t)row*DD + l15 + 16*nt] = d[nt]*inv*gamc[nt] + betc[nt];
    }
  }
}

// ---------------- K2: full-MFMA hyper stage 1 ----------------
// logits = x@clf (hi/lo split both operands, 3 cross terms); wave-group softmax;
// assign hi/lo written; hf = assign^T @ x via MFMA (A2 through per-wave LDS amat),
// register-accumulated, block-reduced into hf_part[b][blk] (no atomics).
__global__ __launch_bounds__(256, 3)
void k2_hyper1(const float* __restrict__ x, const float* __restrict__ clf,
               unsigned short* __restrict__ assign_hi, unsigned short* __restrict__ assign_lo,
               float* __restrict__ hf_part)
{
  __shared__ __align__(16) float lbuf[4224];   // union: amat 4x[32][33] | red 2x[32][65]
  const int lane = threadIdx.x & 63;
  const int wid  = threadIdx.x >> 6;
  const int l15  = lane & 15;
  const int lg   = lane >> 4;
  const int b    = blockIdx.x / CPB2N;
  const int blk  = blockIdx.x % CPB2N;
  float* amat = lbuf + wid*1056;               // [32][33] f32 per wave

  // clf B-fragments (hoisted): Q[l15 -> e+16nt][k = 32kc+8lg+j]
  short8 bch[2][2], bcl[2][2];
  #pragma unroll
  for (int kc = 0; kc < 2; ++kc)
    #pragma unroll
    for (int nt = 0; nt < 2; ++nt){
      float v[8];
      #pragma unroll
      for (int j = 0; j < 8; ++j)
        v[j] = clf[(size_t)(32*kc + 8*lg + j)*EE + 16*nt + l15];
      bch[kc][nt] = pack_hi8(v);
      bcl[kc][nt] = pack_lo8(v, bch[kc][nt]);
    }

  f32x4 acc2[2][4];                            // hf partial: [et][dt], e=16et+4lg+q, d=16dt+l15
  #pragma unroll
  for (int et = 0; et < 2; ++et)
    #pragma unroll
    for (int dt = 0; dt < 4; ++dt) acc2[et][dt] = (f32x4){0.f,0.f,0.f,0.f};

  const int wslot = blk*4 + wid;               // 0..191
  #pragma unroll 1
  for (int s = 0; s < 2; ++s){
    const int c = wslot + s*192;               // chunk 0..383 (32 rows each)
    const size_t grb = (size_t)b*MM + (size_t)c*32;

    #pragma unroll 1
    for (int h = 0; h < 2; ++h){
      short8 axh[2], axl[2];
      #pragma unroll
      for (int kc = 0; kc < 2; ++kc){
        const float* p = x + (grb + 16*h + l15)*DD + 32*kc + 8*lg;
        float v[8];
        const float4 p0 = *reinterpret_cast<const float4*>(p);
        const float4 p1 = *reinterpret_cast<const float4*>(p + 4);
        v[0]=p0.x; v[1]=p0.y; v[2]=p0.z; v[3]=p0.w;
        v[4]=p1.x; v[5]=p1.y; v[6]=p1.z; v[7]=p1.w;
        axh[kc] = pack_hi8(v); axl[kc] = pack_lo8(v, axh[kc]);
      }
      f32x4 accL[2] = {(f32x4){0.f,0.f,0.f,0.f},(f32x4){0.f,0.f,0.f,0.f}};
      #pragma unroll
      for (int kc = 0; kc < 2; ++kc)
        #pragma unroll
        for (int nt = 0; nt < 2; ++nt){
          accL[nt] = __builtin_amdgcn_mfma_f32_16x16x32_bf16(axh[kc], bch[kc][nt], accL[nt], 0, 0, 0);
          accL[nt] = __builtin_amdgcn_mfma_f32_16x16x32_bf16(axh[kc], bcl[kc][nt], accL[nt], 0, 0, 0);
          accL[nt] = __builtin_amdgcn_mfma_f32_16x16x32_bf16(axl[kc], bch[kc][nt], accL[nt], 0, 0, 0);
        }
      // softmax over e (32 values: 16 lanes x 2 nt) per row
      #pragma unroll
      for (int q = 0; q < 4; ++q){
        const float l0 = accL[0][q], l1 = accL[1][q];
        float mx = fmaxf(l0, l1);
        #pragma unroll
        for (int off = 8; off; off >>= 1) mx = fmaxf(mx, __shfl_xor(mx, off));
        const float e0 = expf(l0 - mx), e1 = expf(l1 - mx);
        float sm = e0 + e1;
        #pragma unroll
        for (int off = 8; off; off >>= 1) sm += __shfl_xor(sm, off);
        const float inv = 1.f / sm;
        const float a0 = e0*inv, a1 = e1*inv;
        const int rloc = 16*h + 4*lg + q;
        const size_t row = grb + rloc;
        const unsigned short h0 = bf16of(a0);
        const unsigned short h1 = bf16of(a1);
        assign_hi[row*EE + l15]      = h0;
        assign_hi[row*EE + 16 + l15] = h1;
        assign_lo[row*EE + l15]      = bf16of(a0 - f32of(h0));
        assign_lo[row*EE + 16 + l15] = bf16of(a1 - f32of(h1));
        amat[rloc*33 + l15]      = a0;
        amat[rloc*33 + 16 + l15] = a1;
      }
    }
    __builtin_amdgcn_wave_barrier();
    // A2 = assign^T fragments (hi/lo) from amat
    short8 a2h[2], a2l[2];
    #pragma unroll
    for (int et = 0; et < 2; ++et){
      float v[8];
      #pragma unroll
      for (int j = 0; j < 8; ++j)
        v[j] = amat[(8*lg + j)*33 + 16*et + l15];
      a2h[et] = pack_hi8(v); a2l[et] = pack_lo8(v, a2h[et]);
    }
    // B2 = x^T fragments (hi only), hf MFMAs
    #pragma unroll
    for (int dt = 0; dt < 4; ++dt){
      float v[8];
      #pragma unroll
      for (int j = 0; j < 8; ++j)
        v[j] = x[(grb + 8*lg + j)*DD + 16*dt + l15];
      const short8 b2 = pack_hi8(v);
      #pragma unroll
      for (int et = 0; et < 2; ++et){
        acc2[et][dt] = __builtin_amdgcn_mfma_f32_16x16x32_bf16(a2h[et], b2, acc2[et][dt], 0, 0, 0);
        acc2[et][dt] = __builtin_amdgcn_mfma_f32_16x16x32_bf16(a2l[et], b2, acc2[et][dt], 0, 0, 0);
      }
    }
    __builtin_amdgcn_wave_barrier();
  }

  // block-level reduce of acc2 (4 waves -> 1), one slot per block, no atomics
  __syncthreads();
  float* red = lbuf;                           // [2][32*65]
  if (wid < 2){
    #pragma unroll
    for (int et = 0; et < 2; ++et)
      #pragma unroll
      for (int dt = 0; dt < 4; ++dt)
        #pragma unroll
        for (int q = 0; q < 4; ++q)
          red[wid*2080 + (16*et + 4*lg + q)*65 + 16*dt + l15] = acc2[et][dt][q];
  }
  __syncthreads();
  if (wid >= 2){
    #pragma unroll
    for (int et = 0; et < 2; ++et)
      #pragma unroll
      for (int dt = 0; dt < 4; ++dt)
        #pragma unroll
        for (int q = 0; q < 4; ++q)
          red[(wid-2)*2080 + (16*et + 4*lg + q)*65 + 16*dt + l15] += acc2[et][dt][q];
  }
  __syncthreads();
  float* dst = hf_part + ((size_t)b*CPB2N + blk)*(EE*DD);
  for (int i = threadIdx.x; i < EE*DD; i += 256){
    const int e = i >> 6, d = i & 63;
    dst[i] = red[e*65 + d] + red[2080 + e*65 + d];
  }
}

// ---------------- K3: sum hf_part slots; ho = relu(em @ hf) + hf; emit transposed bf16 hi/lo ----------------
__global__ void k3_edge(const float* __restrict__ hf_part, const float* __restrict__ em,
                        unsigned short* __restrict__ ho_hi, unsigned short* __restrict__ ho_lo)
{
  __shared__ float ems[EE*EE];
  __shared__ float hfs[EE*DD];
  const int b = blockIdx.x;
  const int tid = threadIdx.x;
  for (int i = tid; i < EE*EE; i += 256) ems[i] = em[i];
  for (int i = tid; i < EE*DD; i += 256){
    const float* p = hf_part + (size_t)b*CPB2N*(EE*DD) + i;
    float s0=0.f, s1=0.f, s2=0.f, s3=0.f;
    #pragma unroll
    for (int k = 0; k < CPB2N; k += 4){
      s0 += p[(size_t)(k+0)*EE*DD]; s1 += p[(size_t)(k+1)*EE*DD];
      s2 += p[(size_t)(k+2)*EE*DD]; s3 += p[(size_t)(k+3)*EE*DD];
    }
    hfs[i] = (s0+s1)+(s2+s3);
  }
  __syncthreads();
  for (int i = tid; i < EE*DD; i += 256){
    const int e = i >> 6, d = i & 63;
    float acc = 0.f;
    #pragma unroll
    for (int f = 0; f < EE; ++f) acc = fmaf(ems[e*EE+f], hfs[f*DD+d], acc);
    const float v = fmaxf(acc, 0.f) + hfs[e*DD+d];
    const unsigned short hi = bf16of(v);
    const unsigned short lo = bf16of(v - f32of(hi));
    ho_hi[((size_t)b*DD + d)*EE + e] = hi;
    ho_lo[((size_t)b*DD + d)*EE + e] = lo;
  }
}

// ---------------- K4: y = relu(assign @ ho) via split-MFMA; out2 = LN(y+x); xout = 0.5*(out1+out2) ----------------
__global__ __launch_bounds__(256, 4)
void k4_combine(const float* __restrict__ x, const float* __restrict__ out1,
                const unsigned short* __restrict__ assign_hi,
                const unsigned short* __restrict__ assign_lo,
                const unsigned short* __restrict__ ho_hi,
                const unsigned short* __restrict__ ho_lo,
                const float* __restrict__ hg, const float* __restrict__ hb,
                float* __restrict__ xout)
{
  const int lane = threadIdx.x & 63;
  const int wid  = threadIdx.x >> 6;
  const int b    = blockIdx.x / CPB4;
  const int blk  = blockIdx.x % CPB4;
  const int l15  = lane & 15;
  const int lg   = lane >> 4;

  short8 bwh[4], bwl[4];
  #pragma unroll
  for (int nt = 0; nt < 4; ++nt){
    const size_t off = ((size_t)b*DD + l15 + 16*nt)*EE + 8*lg;
    bwh[nt] = *reinterpret_cast<const short8*>(ho_hi + off);
    bwl[nt] = *reinterpret_cast<const short8*>(ho_lo + off);
  }

  float gamc[4], betc[4];
  #pragma unroll
  for (int nt = 0; nt < 4; ++nt){
    gamc[nt] = hg[l15 + 16*nt];
    betc[nt] = hb[l15 + 16*nt];
  }

  const int tpb = MM / 16;
  for (int tl = blk*4 + wid; tl < tpb; tl += CPB4*4){
    const size_t r0 = (size_t)b*MM + tl*16;

    const short8 afh = *reinterpret_cast<const short8*>(assign_hi + (r0 + l15)*EE + 8*lg);
    const short8 afl = *reinterpret_cast<const short8*>(assign_lo + (r0 + l15)*EE + 8*lg);

    f32x4 acc[4];
    #pragma unroll
    for (int nt = 0; nt < 4; ++nt) acc[nt] = (f32x4){0.f,0.f,0.f,0.f};
    #pragma unroll
    for (int nt = 0; nt < 4; ++nt){
      acc[nt] = __builtin_amdgcn_mfma_f32_16x16x32_bf16(afh, bwh[nt], acc[nt], 0, 0, 0);
      acc[nt] = __builtin_amdgcn_mfma_f32_16x16x32_bf16(afh, bwl[nt], acc[nt], 0, 0, 0);
      acc[nt] = __builtin_amdgcn_mfma_f32_16x16x32_bf16(afl, bwh[nt], acc[nt], 0, 0, 0);
    }

    #pragma unroll
    for (int q = 0; q < 4; ++q){
      const size_t row = r0 + 4*lg + q;
      float s[4];
      float rs = 0.f;
      #pragma unroll
      for (int nt = 0; nt < 4; ++nt){
        const float xr = x[row*DD + l15 + 16*nt];
        s[nt] = fmaxf(acc[nt][q], 0.f) + xr;
        rs += s[nt];
      }
      #pragma unroll
      for (int off = 8; off; off >>= 1) rs += __shfl_xor(rs, off);
      const float mean = rs * (1.f/DD);
      float d[4]; float vs = 0.f;
      #pragma unroll
      for (int nt = 0; nt < 4; ++nt){ d[nt] = s[nt] - mean; vs = fmaf(d[nt], d[nt], vs); }
      #pragma unroll
      for (int off = 8; off; off >>= 1) vs += __shfl_xor(vs, off);
      const float inv = rsqrtf(vs * (1.f/DD) + LN_EPS);
      #pragma unroll
      for (int nt = 0; nt < 4; ++nt){
        const float o2 = d[nt]*inv*gamc[nt] + betc[nt];
        const float o1 = out1[row*DD + l15 + 16*nt];
        xout[row*DD + l15 + 16*nt] = 0.5f*(o1 + o2);
      }
    }
  }
}

extern "C" void kernel_launch(void* const* d_in, const int* in_sizes, int n_in,
                              void* d_out, int out_size, void* d_ws, size_t ws_size,
                              hipStream_t stream)
{
  (void)in_sizes; (void)n_in; (void)out_size; (void)ws_size;
  const float* x0  = (const float*)d_in[0];
  const float* W1  = (const float*)d_in[1];
  const float* b1  = (const float*)d_in[2];
  const float* W2  = (const float*)d_in[3];
  const float* b2  = (const float*)d_in[4];
  const float* lng = (const float*)d_in[5];
  const float* lnb = (const float*)d_in[6];
  const float* clf = (const float*)d_in[7];
  const float* em  = (const float*)d_in[8];
  const float* hg  = (const float*)d_in[9];
  const float* hb  = (const float*)d_in[10];
  float* out = (float*)d_out;

  // workspace: x ping f32 | hf_part f32 [BB][CPB2N][EE*DD] | assign hi/lo bf16 | ho hi/lo bf16
  float* ws_x = (float*)d_ws;
  float* hf_part = ws_x + (size_t)ROWS*DD;
  unsigned short* assign_hi = (unsigned short*)(hf_part + (size_t)BB*CPB2N*EE*DD);
  unsigned short* assign_lo = assign_hi + (size_t)ROWS*EE;
  unsigned short* ho_hi     = assign_lo + (size_t)ROWS*EE;
  unsigned short* ho_lo     = ho_hi + (size_t)BB*DD*EE;

  for (int i = 0; i < 3; ++i){
    const float* xin = (i == 0) ? x0 : ws_x;
    float* xout = (i == 2) ? out : ws_x;
    k1_stgcn<<<1536, 256, 0, stream>>>(xin, W1 + i*DD*DD, b1 + i*DD,
                                       W2 + i*DD*DD, b2 + i*DD,
                                       lng + i*DD, lnb + i*DD, out);
    k2_hyper1<<<BB*CPB2N, 256, 0, stream>>>(xin, clf, assign_hi, assign_lo, hf_part);
    k3_edge<<<BB, 256, 0, stream>>>(hf_part, em, ho_hi, ho_lo);
    k4_combine<<<BB*CPB4, 256, 0, stream>>>(xin, out, assign_hi, assign_lo, ho_hi, ho_lo, hg, hb, xout);
  }
}